// Round 11
// baseline (295.579 us; speedup 1.0000x reference)
//
#include <hip/hip_runtime.h>
#include <math.h>

// Problem constants (16 x 1 x 1024 x 1024 fp32 pred/mask -> scalar fp32 loss)
#define BATCH 16
#define H 1024
#define W 1024
#define TILE 64
#define TILES_X (W / TILE)            // 16
#define TPB 2                         // tiles per block (vertically adjacent)
#define TYG (H / TILE / TPB)          // 8 tile-groups per column
#define NTG (TILES_X * TYG)           // 128 tile-groups per batch image
#define HDIM 96
#define SCOLS 97   // stride 97 % 32 == 1 -> scans and lookups land 2-way/bank max (free)
#define SEG  24    // scan segment length: 4 threads per 96-line

// d_ws: part[(c*BATCH + b)*NTG + group], c in [0,5) -- 40 KB. NO atomics
// (R4: contended atomicAdds serialized the GPU at ~115 atomics/us).
//
// R10 lessons: shape optimum is TILE=64 (smaller AND bigger both regress).
// Kernel is latency-bound (per-SIMD VALU ~14%): each block's serial head is
// ~900cy of cold HBM loads. R11: 2 tiles per block, tile-B operands prefetched
// into registers during tile-A's P2/P3 window -> tile B starts hot. P4 and
// block overhead amortize 2x; tile B's top halo is L2-warm from tile A.

// DPP wave64 sum: lane 63 holds the full sum afterwards (VALU pipe, no LDS).
__device__ __forceinline__ float wave_sum_dpp(float x) {
    int t;
    t = __builtin_amdgcn_update_dpp(0, __float_as_int(x), 0x111, 0xf, 0xf, true); // row_shr:1
    x += __int_as_float(t);
    t = __builtin_amdgcn_update_dpp(0, __float_as_int(x), 0x112, 0xf, 0xf, true); // row_shr:2
    x += __int_as_float(t);
    t = __builtin_amdgcn_update_dpp(0, __float_as_int(x), 0x114, 0xf, 0xf, true); // row_shr:4
    x += __int_as_float(t);
    t = __builtin_amdgcn_update_dpp(0, __float_as_int(x), 0x118, 0xf, 0xf, true); // row_shr:8
    x += __int_as_float(t);
    t = __builtin_amdgcn_update_dpp(0, __float_as_int(x), 0x142, 0xf, 0xf, true); // row_bcast:15
    x += __int_as_float(t);
    t = __builtin_amdgcn_update_dpp(0, __float_as_int(x), 0x143, 0xf, 0xf, true); // row_bcast:31
    x += __int_as_float(t);
    return x;  // valid in lane 63
}

// Row-segment load for the scan (6x float4, zero-padded OOB).
__device__ __forceinline__ void load_scan_row(const float* __restrict__ mimg,
                                              int ty0, int tx0, int row, int seg,
                                              float v[SEG]) {
    const int gy  = ty0 - 16 + row;
    const int gx0 = tx0 - 16 + seg * SEG;
    const bool rowok = (gy >= 0) && (gy < H);
    const float* rp = mimg + (size_t)gy * W;
    #pragma unroll
    for (int j = 0; j < 6; ++j) {
        int gx = gx0 + 4 * j;                  // 16B-aligned; chunk fully in or out
        float4 t;
        if (rowok && gx >= 0 && gx < W) t = *(const float4*)(rp + gx);
        else                            t = make_float4(0.f, 0.f, 0.f, 0.f);
        v[4 * j + 0] = t.x; v[4 * j + 1] = t.y;
        v[4 * j + 2] = t.z; v[4 * j + 3] = t.w;
    }
}

// Row prefix + cross-segment shfl combine + LDS write (phase 1 tail).
__device__ __forceinline__ void scan_and_store_row(float v[SEG], int row, int seg,
                                                   float* __restrict__ sat) {
    #pragma unroll
    for (int i = 1; i < SEG; ++i) v[i] += v[i - 1];
    float tot = v[SEG - 1];
    float inc = tot;
    float t1 = __shfl_up(inc, 1); if (seg >= 1) inc += t1;
    float t2 = __shfl_up(inc, 2); if (seg >= 2) inc += t2;
    const float off = inc - tot;
    const int base = row * SCOLS + seg * SEG;
    #pragma unroll
    for (int i = 0; i < SEG; ++i) sat[base + i] = v[i] + off;
}

// Phase 2: column prefix over the row-scanned LDS buffer.
__device__ __forceinline__ void col_scan(float* __restrict__ sat, int tid) {
    const int col = tid >> 2, seg = tid & 3;
    const int base = (seg * SEG) * SCOLS + col;
    float v[SEG];
    #pragma unroll
    for (int i = 0; i < SEG; ++i) v[i] = sat[base + i * SCOLS];
    #pragma unroll
    for (int i = 1; i < SEG; ++i) v[i] += v[i - 1];
    float tot = v[SEG - 1];
    float inc = tot;
    float t1 = __shfl_up(inc, 1); if (seg >= 1) inc += t1;
    float t2 = __shfl_up(inc, 2); if (seg >= 2) inc += t2;
    const float off = inc - tot;
    #pragma unroll
    for (int i = 0; i < SEG; ++i) sat[base + i * SCOLS] = v[i] + off;
}

// Phase 3: per-pixel fused compute for one tile, accumulating into s_*.
__device__ __forceinline__ void compute_tile(const float* __restrict__ sat,
                                             const float4 m4[2], const float4 p4[2],
                                             int tid,
                                             float& s_w, float& s_wb, float& s_in,
                                             float& s_un, float& s_mae) {
    __builtin_amdgcn_s_setprio(1);
    #pragma unroll
    for (int i = 0; i < 2; ++i) {
        const int rc  = (tid >> 4) + 32 * i + 16;   // halo row of pixel
        const int x0c = ((tid & 15) << 2) + 16;     // halo col of pixel q=0

        float w[4] = {0.f, 0.f, 0.f, 0.f};

        #pragma unroll
        for (int j = 0; j < 3; ++j) {
            constexpr int PP[3] = {1, 7, 15};
            constexpr float INV[3] = {1.0f / 9.0f, 1.0f / 225.0f, 1.0f / 961.0f};
            const int p = PP[j];
            const int bt = (rc + p) * SCOLS + x0c - 16;      // top row (r2), biased
            const int bb = (rc - p - 1) * SCOLS + x0c - 16;  // bottom row (r1)
            #pragma unroll
            for (int q = 0; q < 4; ++q) {
                float s = sat[bt + (16 + p + q)] - sat[bb + (16 + p + q)]
                        - sat[bt + (15 - p + q)] + sat[bb + (15 - p + q)];
                w[q] += fabsf(s * INV[j] - (&m4[i].x)[q]);
            }
        }

        #pragma unroll
        for (int q = 0; q < 4; ++q) {
            float m  = (&m4[i].x)[q];
            float pr = (&p4[i].x)[q];
            float weit = 1.0f + 5.0f * w[q];
            float t    = __expf(-fabsf(pr));                 // shared by bce & sigmoid
            float bce  = fmaxf(pr, 0.0f) - pr * m + __logf(1.0f + t);
            float u    = __builtin_amdgcn_rcpf(1.0f + t);    // 1/(1+e^-|pr|)
            float sig  = (pr >= 0.0f) ? u : 1.0f - u;

            s_w   += weit;
            s_wb  += weit * bce;
            s_in  += sig * m * weit;
            s_un  += (sig + m) * weit;
            s_mae += fabsf(sig - m);
        }
    }
    __builtin_amdgcn_s_setprio(0);
}

__global__ __launch_bounds__(512, 6)   // 85-VGPR budget for the cross-tile prefetch set
void adaptive_loss_main(const float* __restrict__ pred,
                        const float* __restrict__ mask,
                        float* __restrict__ part) {
    __shared__ float sat[HDIM * SCOLS];
    __shared__ float red[8][5];

    const int tid = threadIdx.x;
    const int b   = blockIdx.z;
    const int ty0a = (blockIdx.y * TPB) * TILE;      // tile A
    const int ty0b = ty0a + TILE;                    // tile B (vertically adjacent)
    const int tx0  = blockIdx.x * TILE;
    const float* mimg = mask + (size_t)b * H * W;
    const float* pimg = pred + (size_t)b * H * W;

    const int srow = tid >> 2, sseg = tid & 3;

    float s_w = 0.0f, s_wb = 0.0f, s_in = 0.0f, s_un = 0.0f, s_mae = 0.0f;

    // ---- Tile A, phase 0+1: load + row scan + LDS write ----
    if (tid < 4 * HDIM) {
        float va[SEG];
        load_scan_row(mimg, ty0a, tx0, srow, sseg, va);
        scan_and_store_row(va, srow, sseg, sat);
    }
    __syncthreads();

    // ---- Prefetch EVERYTHING else into the A-P2/P3 window:
    //      A's m/p operands (used in P3a), B's scan rows (used in P1b, ~2500cy
    //      away -> HBM latency fully hidden), B's m/p operands (used in P3b). ----
    float4 m4a[2], p4a[2];
    #pragma unroll
    for (int i = 0; i < 2; ++i) {
        int y  = (tid >> 4) + 32 * i;
        int x4 = (tid & 15) << 2;
        size_t off = (size_t)(ty0a + y) * W + (tx0 + x4);
        m4a[i] = *(const float4*)(mimg + off);
        p4a[i] = *(const float4*)(pimg + off);
    }
    float vb[SEG];
    if (tid < 4 * HDIM) load_scan_row(mimg, ty0b, tx0, srow, sseg, vb);
    float4 m4b[2], p4b[2];
    #pragma unroll
    for (int i = 0; i < 2; ++i) {
        int y  = (tid >> 4) + 32 * i;
        int x4 = (tid & 15) << 2;
        size_t off = (size_t)(ty0b + y) * W + (tx0 + x4);
        m4b[i] = *(const float4*)(mimg + off);
        p4b[i] = *(const float4*)(pimg + off);
    }

    // ---- Tile A, phase 2: col scan ----
    if (tid < 4 * HDIM) col_scan(sat, tid);
    __syncthreads();

    // ---- Tile A, phase 3 ----
    compute_tile(sat, m4a, p4a, tid, s_w, s_wb, s_in, s_un, s_mae);
    __syncthreads();   // all P3a reads done before B overwrites sat

    // ---- Tile B, phase 1: row scan from prefetched regs (starts hot) ----
    if (tid < 4 * HDIM) scan_and_store_row(vb, srow, sseg, sat);
    __syncthreads();

    // ---- Tile B, phase 2 ----
    if (tid < 4 * HDIM) col_scan(sat, tid);
    __syncthreads();

    // ---- Tile B, phase 3 ----
    compute_tile(sat, m4b, p4b, tid, s_w, s_wb, s_in, s_un, s_mae);

    // ---- Phase 4 (once per block): DPP wave reduction, cross-wave via red[],
    //      5 plain stores to unique addresses ----
    s_w   = wave_sum_dpp(s_w);
    s_wb  = wave_sum_dpp(s_wb);
    s_in  = wave_sum_dpp(s_in);
    s_un  = wave_sum_dpp(s_un);
    s_mae = wave_sum_dpp(s_mae);

    int wave = tid >> 6, lane = tid & 63;
    if (lane == 63) {
        red[wave][0] = s_w;  red[wave][1] = s_wb; red[wave][2] = s_in;
        red[wave][3] = s_un; red[wave][4] = s_mae;
    }
    __syncthreads();
    if (tid < 5) {
        float r = 0.0f;
        #pragma unroll
        for (int wv = 0; wv < 8; ++wv) r += red[wv][tid];
        const int group = blockIdx.y * TILES_X + blockIdx.x;
        part[((size_t)tid * BATCH + b) * NTG + group] = r;
    }
}

// Finalize: one block, 1024 threads. Wave w reduces batch w (128 groups, 2 per
// lane, coalesced comp-major loads), shuffle-reduce, thread 0 scalar epilogue.
__global__ __launch_bounds__(1024)
void adaptive_loss_finalize(const float* __restrict__ part,
                            float* __restrict__ out) {
    __shared__ float sums[BATCH][5];
    const int wv   = threadIdx.x >> 6;   // 0..15 == batch
    const int lane = threadIdx.x & 63;

    float v[5];
    #pragma unroll
    for (int c = 0; c < 5; ++c) {
        float s = 0.0f;
        #pragma unroll
        for (int r = 0; r < NTG / 64; ++r)
            s += part[((size_t)c * BATCH + wv) * NTG + r * 64 + lane];
        v[c] = s;
    }
    #pragma unroll
    for (int off = 32; off > 0; off >>= 1) {
        #pragma unroll
        for (int c = 0; c < 5; ++c) v[c] += __shfl_down(v[c], off);
    }
    if (lane == 0) {
        #pragma unroll
        for (int c = 0; c < 5; ++c) sums[wv][c] = v[c];
    }
    __syncthreads();

    if (threadIdx.x == 0) {
        float smae = 0.0f;
        for (int b = 0; b < BATCH; ++b) smae += sums[b][4];
        float mae = smae / (float)((size_t)BATCH * H * W);
        float tot = 0.0f;
        for (int b = 0; b < BATCH; ++b) {
            float Sw  = sums[b][0];
            float Swb = sums[b][1];
            float Si  = sums[b][2];
            float Su  = sums[b][3];
            float wbce = Swb / Sw;
            float wiou = 1.0f - (Si + 1.0f) / (Su - Si + 1.0f);
            float wmae = mae * Sw / (Sw - (float)(H * W));
            tot += 0.7f * (wbce + wiou + wmae);
        }
        out[0] = tot / (float)BATCH;
    }
}

extern "C" void kernel_launch(void* const* d_in, const int* in_sizes, int n_in,
                              void* d_out, int out_size, void* d_ws, size_t ws_size,
                              hipStream_t stream) {
    const float* pred = (const float*)d_in[0];
    const float* mask = (const float*)d_in[1];
    float* part = (float*)d_ws;   // 5 * BATCH * NTG floats = 40 KB

    dim3 grid(TILES_X, TYG, BATCH);   // 16 x 8 x 16 = 2048 blocks, 2 tiles each
    adaptive_loss_main<<<grid, 512, 0, stream>>>(pred, mask, part);
    adaptive_loss_finalize<<<1, 1024, 0, stream>>>(part, (float*)d_out);
}